// Round 9
// baseline (1222.013 us; speedup 1.0000x reference)
//
#include <hip/hip_runtime.h>

#define DD 128
#define N_NODE 10000
#define N_EDGE 40000
#define N_LAYER 15

typedef unsigned short U16;
typedef __attribute__((ext_vector_type(8))) short short8;
typedef __attribute__((ext_vector_type(4))) float f32x4;

enum { A_BF16 = 0, A_EDGE, A_NODE, A_ENCIN, A_ERAW };
enum { EPI_F = 0, EPI_EDGE, EPI_NODE, EPI_DEC };

// Wt layout offsets (bf16 elements), [n=128][Kpad] per matrix
#define OFF_FV1 0
#define OFF_FV2 4096
#define OFF_FV3 20480
#define OFF_FE1 36864
#define OFF_FE2 40960
#define OFF_FE3 57344
#define OFF_GE1 73728     /* stride 49152 (Kpad=384) */
#define OFF_GE2 811008    /* stride 16384 */
#define OFF_GE3 1056768
#define OFF_GN1 1302528   /* stride 32768 (Kpad=256) */
#define OFF_GN2 1794048
#define OFF_GN3 2039808
#define OFF_DE1 2285568
#define OFF_DE2 2301952
#define WT_TOTAL 2318336

static __device__ __forceinline__ U16 f2b(float f) {
    union { float f; unsigned u; } x; x.f = f;
    unsigned u = x.u;
    return (U16)((u + 0x7fffu + ((u >> 16) & 1u)) >> 16);
}
static __device__ __forceinline__ float b2f(U16 u) {
    union { unsigned u; float f; } x; x.u = ((unsigned)u) << 16;
    return x.f;
}

// workgroup barrier draining ONLY lgkmcnt: in-flight global prefetch loads
// (vmcnt) survive the barrier.
static __device__ __forceinline__ void wgb() {
    __asm__ __volatile__("s_waitcnt lgkmcnt(0)\n\ts_barrier" ::: "memory");
}

struct I4x4 { int4 a, b, c, d; };

// ---------------- weight transpose+cast: W[K][128] f32 -> Wt[n][Kpad] bf16 ----
__global__ __launch_bounds__(256)
void wprep(const float* fv1, const float* fv2, const float* fv3,
           const float* fe1, const float* fe2, const float* fe3,
           const float* ge1, const float* ge2, const float* ge3,
           const float* gn1, const float* gn2, const float* gn3,
           const float* de1, const float* de2, U16* Wt)
{
    int b = blockIdx.x;
    const float* src; U16* dst; int K, Kpad, k0;
    if      (b < 1)   { src = fv1; K = 12;  Kpad = 32;  dst = Wt + OFF_FV1; k0 = b * 32; }
    else if (b < 5)   { src = fv2; K = 128; Kpad = 128; dst = Wt + OFF_FV2; k0 = (b-1)*32; }
    else if (b < 9)   { src = fv3; K = 128; Kpad = 128; dst = Wt + OFF_FV3; k0 = (b-5)*32; }
    else if (b < 10)  { src = fe1; K = 4;   Kpad = 32;  dst = Wt + OFF_FE1; k0 = (b-9)*32; }
    else if (b < 14)  { src = fe2; K = 128; Kpad = 128; dst = Wt + OFF_FE2; k0 = (b-10)*32; }
    else if (b < 18)  { src = fe3; K = 128; Kpad = 128; dst = Wt + OFF_FE3; k0 = (b-14)*32; }
    else if (b < 198) { int r = b-18,  mi = r/12, s = r%12; src = ge1 + (size_t)mi*384*128; K = 384; Kpad = 384; dst = Wt + OFF_GE1 + (size_t)mi*49152; k0 = s*32; }
    else if (b < 258) { int r = b-198, mi = r/4,  s = r%4;  src = ge2 + (size_t)mi*16384;   K = 128; Kpad = 128; dst = Wt + OFF_GE2 + (size_t)mi*16384; k0 = s*32; }
    else if (b < 318) { int r = b-258, mi = r/4,  s = r%4;  src = ge3 + (size_t)mi*16384;   K = 128; Kpad = 128; dst = Wt + OFF_GE3 + (size_t)mi*16384; k0 = s*32; }
    else if (b < 438) { int r = b-318, mi = r/8,  s = r%8;  src = gn1 + (size_t)mi*32768;   K = 256; Kpad = 256; dst = Wt + OFF_GN1 + (size_t)mi*32768; k0 = s*32; }
    else if (b < 498) { int r = b-438, mi = r/4,  s = r%4;  src = gn2 + (size_t)mi*16384;   K = 128; Kpad = 128; dst = Wt + OFF_GN2 + (size_t)mi*16384; k0 = s*32; }
    else if (b < 558) { int r = b-498, mi = r/4,  s = r%4;  src = gn3 + (size_t)mi*16384;   K = 128; Kpad = 128; dst = Wt + OFF_GN3 + (size_t)mi*16384; k0 = s*32; }
    else if (b < 562) { src = de1; K = 128; Kpad = 128; dst = Wt + OFF_DE1; k0 = (b-558)*32; }
    else              { src = de2; K = 128; Kpad = 128; dst = Wt + OFF_DE2; k0 = (b-562)*32; }

    __shared__ float T[32][129];
    #pragma unroll
    for (int i = 0; i < 16; ++i) {
        int l = threadIdx.x + i * 256;
        int kk = l >> 7, n = l & 127;
        int kg = k0 + kk;
        T[kk][n] = (kg < K) ? src[(size_t)kg * 128 + n] : 0.f;
    }
    __syncthreads();
    int n = threadIdx.x >> 1, h = threadIdx.x & 1;
    union { U16 u[16]; int4 v[2]; } o;
    #pragma unroll
    for (int j = 0; j < 16; ++j) o.u[j] = f2b(T[h * 16 + j][n]);
    int4* d = (int4*)(dst + (size_t)n * Kpad + k0 + h * 16);
    d[0] = o.v[0]; d[1] = o.v[1];
}

// ---------------- CSR build (sender-sorted) ----------------------------------
__global__ __launch_bounds__(256)
void csr_hist(const int* __restrict__ edges, int* __restrict__ cnt, int Eg)
{
    int e = blockIdx.x * 256 + threadIdx.x;
    if (e < Eg) atomicAdd(&cnt[edges[2 * e]], 1);
}

__global__ __launch_bounds__(256)
void csr_scan(const int* __restrict__ cnt, int* __restrict__ rowptr,
              int* __restrict__ cursor, int n)
{
    __shared__ int ps[256];
    int t = threadIdx.x, base = t * 40;
    int s = 0;
    for (int j = 0; j < 40; ++j) if (base + j < n) s += cnt[base + j];
    ps[t] = s; __syncthreads();
    for (int off = 1; off < 256; off <<= 1) {
        int v = (t >= off) ? ps[t - off] : 0;
        __syncthreads();
        ps[t] += v;
        __syncthreads();
    }
    int run = ps[t] - s;   // exclusive prefix
    for (int j = 0; j < 40; ++j) {
        if (base + j < n) {
            rowptr[base + j] = run;
            cursor[base + j] = run;
            run += cnt[base + j];
        }
    }
    if (t == 255) rowptr[n] = ps[255];
}

__global__ __launch_bounds__(256)
void csr_scatter(const int* __restrict__ edges, int* __restrict__ cursor,
                 int* __restrict__ spos, int Eg)
{
    int e = blockIdx.x * 256 + threadIdx.x;
    if (e < Eg) spos[e] = atomicAdd(&cursor[edges[2 * e]], 1);
}

// ---------------- fused 3-layer MLP (MFMA, W-as-A, pipelined K-loop) ---------
// BM=32 rows/block, 128 thr = 2 waves; wave wv covers cols wv*64..wv*64+63.
// Register prefetch depth-3 over 2 LDS buffers; barrier drains lgkmcnt only
// (wgb), so prefetch global loads stay in flight across it.
// Aggregation (A_NODE, k>=128) sums sender-sorted e_emb rows in DOUBLE so the
// result is invariant to csr_scatter's atomic slot permutation (replay-stable).
template<int ASRC, int EPI, int K1>
__global__ __launch_bounds__(128)
void mlp3(const U16* __restrict__ Af,
          const U16* __restrict__ W1, const float* __restrict__ b1,
          const U16* __restrict__ W2, const float* __restrict__ b2,
          const U16* __restrict__ W3, const float* __restrict__ b3,
          U16* __restrict__ outh, float* __restrict__ outf,
          const int* __restrict__ edges, const int* __restrict__ rowptr,
          const int* __restrict__ spos, float* __restrict__ eEs,
          const U16* __restrict__ Vh, const U16* __restrict__ Ehp,
          const float* __restrict__ pos, const float* __restrict__ area,
          const float* __restrict__ info, const float* __restrict__ w3f,
          int M)
{
    __shared__ U16 As[2][32][40];    // [buf][m][k]
    __shared__ U16 Bs[2][128][40];   // [buf][n][k]
    __shared__ U16 Hs[32][136];      // inter-phase activations [m][n]

    const int tid  = threadIdx.x;
    const int row0 = blockIdx.x * 32;
    const int lane = tid & 63;
    const int quad = lane >> 4, l16 = lane & 15;
    const int wn = (tid >> 6) * 64;            // wave n-offset
    const int sr = tid >> 2, sh = tid & 3;     // A staging: row, 8-col chunk
    const int sm = row0 + sr;
    const bool valid = (sm < M);
    const int smc = valid ? sm : 0;

    int si = 0, ri = 0, jbeg = 0, jend = 0;
    if (ASRC == A_EDGE || ASRC == A_ERAW) {
        si = edges[2 * smc]; ri = edges[2 * smc + 1];
    }
    if (ASRC == A_NODE && valid) { jbeg = rowptr[sm]; jend = rowptr[sm + 1]; }

    f32x4 acc[4][2];   // [g][a]: n = wn+16g+quad*4+rg, m = 16a+l16

    auto zacc = [&] {
        #pragma unroll
        for (int g = 0; g < 4; ++g)
            #pragma unroll
            for (int a = 0; a < 2; ++a) acc[g][a] = (f32x4)0.f;
    };

    auto ldA = [&](int c) -> int4 {
        if (ASRC == A_ENCIN || ASRC == A_ERAW) {
            union { U16 u[8]; int4 v; } pk;
            #pragma unroll
            for (int j = 0; j < 8; ++j) pk.u[j] = 0;
            if (valid) {
                if (ASRC == A_ENCIN) {
                    if (sh == 0) {
                        pk.u[0] = f2b(pos[3*sm]); pk.u[1] = f2b(pos[3*sm+1]);
                        pk.u[2] = f2b(pos[3*sm+2]); pk.u[3] = f2b(area[sm]);
                        #pragma unroll
                        for (int j = 0; j < 4; ++j) pk.u[4+j] = f2b(info[j]);
                    } else if (sh == 1) {
                        #pragma unroll
                        for (int j = 0; j < 4; ++j) pk.u[j] = f2b(info[4+j]);
                    }
                } else if (sh == 0) {
                    float dx = pos[3*si]   - pos[3*ri];
                    float dy = pos[3*si+1] - pos[3*ri+1];
                    float dz = pos[3*si+2] - pos[3*ri+2];
                    float nm = sqrtf(dx*dx + dy*dy + dz*dz);
                    pk.u[0] = f2b(dx); pk.u[1] = f2b(dy);
                    pk.u[2] = f2b(dz); pk.u[3] = f2b(nm);
                }
            }
            return pk.v;
        } else if (ASRC == A_NODE && c >= 4) {
            // segmented sum over sender-sorted e_emb rows, DOUBLE accumulation
            double a[8];
            #pragma unroll
            for (int i = 0; i < 8; ++i) a[i] = 0.0;
            if (valid) {
                const float* base = eEs + (c - 4) * 32 + sh * 8;
                for (int j = jbeg; j < jend; ++j) {
                    const float4* r = (const float4*)(base + (size_t)j * 128);
                    float4 x0 = r[0], x1 = r[1];
                    a[0]+=x0.x; a[1]+=x0.y; a[2]+=x0.z; a[3]+=x0.w;
                    a[4]+=x1.x; a[5]+=x1.y; a[6]+=x1.z; a[7]+=x1.w;
                }
            }
            union { U16 u[8]; int4 v; } pk;
            #pragma unroll
            for (int i = 0; i < 8; ++i) pk.u[i] = f2b((float)a[i]);
            return pk.v;
        } else {
            const U16* s;
            if (ASRC == A_BF16)        s = Af + (size_t)smc * K1 + c * 32;
            else if (ASRC == A_EDGE) {
                if (c < 4)             s = Vh  + (size_t)si * 128 + c * 32;
                else if (c < 8)        s = Vh  + (size_t)ri * 128 + (c - 4) * 32;
                else                   s = Ehp + (size_t)smc * 128 + (c - 8) * 32;
            } else                     s = Vh  + (size_t)smc * 128 + c * 32; // A_NODE c<4
            return *(const int4*)(s + sh * 8);
        }
    };

    auto ldW = [&](const U16* W, int Kw, int c) -> I4x4 {
        const int4* s = (const int4*)(W + (size_t)tid * Kw + c * 32);
        I4x4 r; r.a = s[0]; r.b = s[1]; r.c = s[2]; r.d = s[3];
        return r;
    };

    auto wrA = [&](int b, int4 v) { *(int4*)&As[b][sr][sh * 8] = v; };
    auto wrW = [&](int b, I4x4 w) {
        int4* d = (int4*)&Bs[b][tid][0];
        d[0] = w.a; d[1] = w.b; d[2] = w.c; d[3] = w.d;
    };

    auto mfA = [&](int b) {   // A from As[b], W from Bs[b]
        short8 wf[4], af[2];
        #pragma unroll
        for (int g = 0; g < 4; ++g)
            wf[g] = *(const short8*)&Bs[b][wn + 16*g + l16][quad * 8];
        #pragma unroll
        for (int a = 0; a < 2; ++a)
            af[a] = *(const short8*)&As[b][16*a + l16][quad * 8];
        #pragma unroll
        for (int g = 0; g < 4; ++g)
            #pragma unroll
            for (int a = 0; a < 2; ++a)
                acc[g][a] = __builtin_amdgcn_mfma_f32_16x16x32_bf16(
                    wf[g], af[a], acc[g][a], 0, 0, 0);
    };

    auto mfH = [&](int c, int b) {   // A from Hs slice c, W from Bs[b]
        short8 wf[4], af[2];
        #pragma unroll
        for (int g = 0; g < 4; ++g)
            wf[g] = *(const short8*)&Bs[b][wn + 16*g + l16][quad * 8];
        #pragma unroll
        for (int a = 0; a < 2; ++a)
            af[a] = *(const short8*)&Hs[16*a + l16][c * 32 + quad * 8];
        #pragma unroll
        for (int g = 0; g < 4; ++g)
            #pragma unroll
            for (int a = 0; a < 2; ++a)
                acc[g][a] = __builtin_amdgcn_mfma_f32_16x16x32_bf16(
                    wf[g], af[a], acc[g][a], 0, 0, 0);
    };

    auto hwrite = [&](const float* bias) {   // bias + relu -> Hs (bf16)
        #pragma unroll
        for (int g = 0; g < 4; ++g) {
            f32x4 bv = *(const f32x4*)&bias[wn + 16*g + quad*4];
            #pragma unroll
            for (int a = 0; a < 2; ++a) {
                union { U16 u[4]; uint2 q; } pk;
                #pragma unroll
                for (int rg = 0; rg < 4; ++rg)
                    pk.u[rg] = f2b(fmaxf(acc[g][a][rg] + bv[rg], 0.f));
                *(uint2*)&Hs[16*a + l16][wn + 16*g + quad*4] = pk.q;
            }
        }
    };

    int4 ra[3]; I4x4 rw[3];
    constexpr int C1 = K1 / 32;
    constexpr int PD1 = (C1 < 3) ? C1 : 3;

    // ---- phase 1: depth-3 register prefetch, 2 LDS buffers
    zacc();
    #pragma unroll
    for (int p = 0; p < PD1; ++p) { ra[p] = ldA(p); rw[p] = ldW(W1, K1, p); }
    wrA(0, ra[0]); wrW(0, rw[0]);
    wgb();
    #pragma unroll
    for (int c = 0; c < C1; ++c) {
        if (c + 3 < C1) { ra[(c+3)%3] = ldA(c+3); rw[(c+3)%3] = ldW(W1, K1, c+3); }
        if (c + 1 < C1) { wrA((c+1)&1, ra[(c+1)%3]); wrW((c+1)&1, rw[(c+1)%3]); }
        mfA(c & 1);
        wgb();
    }

    // ---- phase 2 (W-only pipeline; A = Hs)
    #pragma unroll
    for (int p = 0; p < 3; ++p) rw[p] = ldW(W2, 128, p);
    hwrite(b1);
    wgb();                      // Hs visible across waves
    zacc();
    wrW(0, rw[0]);
    wgb();
    #pragma unroll
    for (int c = 0; c < 4; ++c) {
        if (c + 3 < 4) rw[(c+3)%3] = ldW(W2, 128, c+3);
        if (c + 1 < 4) wrW((c+1)&1, rw[(c+1)%3]);
        mfH(c, c & 1);
        wgb();
    }

    if (EPI == EPI_DEC) {        // decoder: h2 -> Hs, then dot with w3f
        hwrite(b2);
        wgb();
        int row = tid >> 2, q4 = tid & 3;
        int mg = row0 + row;
        float v = 0.f;
        #pragma unroll
        for (int t = 0; t < 4; ++t) {
            union { int4 i; U16 u[8]; } x;
            x.i = *(const int4*)&Hs[row][q4 * 32 + t * 8];
            const float* wr = w3f + q4 * 32 + t * 8;
            #pragma unroll
            for (int j = 0; j < 8; ++j) v += b2f(x.u[j]) * wr[j];
        }
        v += __shfl_xor(v, 1);
        v += __shfl_xor(v, 2);
        if (q4 == 0 && mg < M) outf[mg] = v + b3[0];
        return;
    }

    // ---- phase 3 (W-only pipeline; A = Hs)
    #pragma unroll
    for (int p = 0; p < 3; ++p) rw[p] = ldW(W3, 128, p);
    hwrite(b2);
    wgb();
    zacc();
    wrW(0, rw[0]);
    wgb();
    #pragma unroll
    for (int c = 0; c < 4; ++c) {
        if (c + 3 < 4) rw[(c+3)%3] = ldW(W3, 128, c+3);
        if (c + 1 < 4) wrW((c+1)&1, rw[(c+1)%3]);
        mfH(c, c & 1);
        wgb();
    }

    // ---- epilogue (no relu)
    #pragma unroll
    for (int a = 0; a < 2; ++a) {
        int mg = row0 + 16*a + l16;
        if (mg >= M) continue;
        int sp = 0;
        if (EPI == EPI_EDGE) sp = spos[mg];
        #pragma unroll
        for (int g = 0; g < 4; ++g) {
            int n0 = wn + 16*g + quad*4;
            f32x4 bv = *(const f32x4*)&b3[n0];
            f32x4 v;
            #pragma unroll
            for (int rg = 0; rg < 4; ++rg) v[rg] = acc[g][a][rg] + bv[rg];
            size_t o = (size_t)mg * 128 + n0;
            if (EPI == EPI_F) {
                *(f32x4*)&outf[o] = v;
            } else {
                f32x4 cc = *(f32x4*)&outf[o];
                cc += v;
                *(f32x4*)&outf[o] = cc;
                union { U16 u[4]; uint2 q; } pk;
                #pragma unroll
                for (int rg = 0; rg < 4; ++rg) pk.u[rg] = f2b(cc[rg]);
                *(uint2*)&outh[o] = pk.q;
                if (EPI == EPI_EDGE)
                    *(f32x4*)&eEs[(size_t)sp * 128 + n0] = v;   // sorted e_emb
            }
        }
    }
}

// in-place LayerNorm over D=128 on fp32 master + bf16 mirror
__global__ __launch_bounds__(256)
void ln_kernel(float* __restrict__ X, const float* __restrict__ g,
               const float* __restrict__ b, U16* __restrict__ Xh, int rows)
{
    int row  = blockIdx.x * 4 + (threadIdx.x >> 6);
    int lane = threadIdx.x & 63;
    if (row >= rows) return;
    float x0 = X[row * DD + lane];
    float x1 = X[row * DD + 64 + lane];
    float s = x0 + x1, q = x0 * x0 + x1 * x1;
    #pragma unroll
    for (int off = 32; off; off >>= 1) {
        s += __shfl_xor(s, off);
        q += __shfl_xor(q, off);
    }
    float mu  = s * (1.f / 128.f);
    float var = q * (1.f / 128.f) - mu * mu;
    float inv = rsqrtf(var + 1e-5f);
    float y0 = (x0 - mu) * inv * g[lane]      + b[lane];
    float y1 = (x1 - mu) * inv * g[64 + lane] + b[64 + lane];
    X[row * DD + lane]       = y0;
    X[row * DD + 64 + lane]  = y1;
    Xh[row * DD + lane]      = f2b(y0);
    Xh[row * DD + 64 + lane] = f2b(y1);
}

extern "C" void kernel_launch(void* const* d_in, const int* in_sizes, int n_in,
                              void* d_out, int out_size, void* d_ws, size_t ws_size,
                              hipStream_t stream)
{
    (void)in_sizes; (void)n_in; (void)out_size; (void)ws_size;

    const float* pos   = (const float*)d_in[0];
    const float* area  = (const float*)d_in[1];
    const float* info  = (const float*)d_in[2];
    const int*   edges = (const int*)d_in[3];
    const float* fv_w1 = (const float*)d_in[4];
    const float* fv_b1 = (const float*)d_in[5];
    const float* fv_w2 = (const float*)d_in[6];
    const float* fv_b2 = (const float*)d_in[7];
    const float* fv_w3 = (const float*)d_in[8];
    const float* fv_b3 = (const float*)d_in[9];
    const float* fv_g  = (const float*)d_in[10];
    const float* fv_bt = (const float*)d_in[11];
    const float* fe_w1 = (const float*)d_in[12];
    const float* fe_b1 = (const float*)d_in[13];
    const float* fe_w2 = (const float*)d_in[14];
    const float* fe_b2 = (const float*)d_in[15];
    const float* fe_w3 = (const float*)d_in[16];
    const float* fe_b3 = (const float*)d_in[17];
    const float* fe_g  = (const float*)d_in[18];
    const float* fe_bt = (const float*)d_in[19];
    const float* ge_w1 = (const float*)d_in[20];
    const float* ge_b1 = (const float*)d_in[21];
    const float* ge_w2 = (const float*)d_in[22];
    const float* ge_b2 = (const float*)d_in[23];
    const float* ge_w3 = (const float*)d_in[24];
    const float* ge_b3 = (const float*)d_in[25];
    const float* gn_w1 = (const float*)d_in[26];
    const float* gn_b1 = (const float*)d_in[27];
    const float* gn_w2 = (const float*)d_in[28];
    const float* gn_b2 = (const float*)d_in[29];
    const float* gn_w3 = (const float*)d_in[30];
    const float* gn_b3 = (const float*)d_in[31];
    const float* de_w1 = (const float*)d_in[32];
    const float* de_b1 = (const float*)d_in[33];
    const float* de_w2 = (const float*)d_in[34];
    const float* de_b2 = (const float*)d_in[35];
    const float* de_w3 = (const float*)d_in[36];
    const float* de_b3 = (const float*)d_in[37];

    // workspace layout (~64 MB)
    char* p = (char*)d_ws;
    float* Vf   = (float*)p;  p += (size_t)N_NODE * 128 * 4;
    float* Ef   = (float*)p;  p += (size_t)N_EDGE * 128 * 4;
    float* eEs  = (float*)p;  p += (size_t)N_EDGE * 128 * 4;
    U16*  Vh    = (U16*)p;    p += (size_t)N_NODE * 128 * 2;
    U16*  Eh    = (U16*)p;    p += (size_t)N_EDGE * 128 * 2;
    U16*  Wt    = (U16*)p;    p += (size_t)WT_TOTAL * 2;
    int*  rowptr = (int*)p;   p += (size_t)(N_NODE + 4) * 4;
    int*  cursor = (int*)p;   p += (size_t)N_NODE * 4;
    int*  cnt    = (int*)p;   p += (size_t)N_NODE * 4;
    int*  spos   = (int*)p;   p += (size_t)N_EDGE * 4;

    const int gbE = (N_EDGE + 31) / 32;   // 1250 blocks (2 waves x 32 rows)
    const int gbN = (N_NODE + 31) / 32;   // 313

    // ---- prep: weights, CSR
    wprep<<<566, 256, 0, stream>>>(fv_w1, fv_w2, fv_w3, fe_w1, fe_w2, fe_w3,
                                   ge_w1, ge_w2, ge_w3, gn_w1, gn_w2, gn_w3,
                                   de_w1, de_w2, Wt);
    hipMemsetAsync(cnt, 0, (size_t)N_NODE * 4, stream);
    csr_hist<<<(N_EDGE + 255) / 256, 256, 0, stream>>>(edges, cnt, N_EDGE);
    csr_scan<<<1, 256, 0, stream>>>(cnt, rowptr, cursor, N_NODE);
    csr_scatter<<<(N_EDGE + 255) / 256, 256, 0, stream>>>(edges, cursor, spos, N_EDGE);

    // ---- edge encoder (eraw fused) -> Ef; LN -> Ef + Eh
    mlp3<A_ERAW, EPI_F, 32><<<gbE, 128, 0, stream>>>(
        nullptr, Wt + OFF_FE1, fe_b1, Wt + OFF_FE2, fe_b2, Wt + OFF_FE3, fe_b3,
        nullptr, Ef, edges, nullptr, nullptr, nullptr, nullptr, nullptr,
        pos, nullptr, nullptr, nullptr, N_EDGE);
    ln_kernel<<<(N_EDGE + 3) / 4, 256, 0, stream>>>(Ef, fe_g, fe_bt, Eh, N_EDGE);

    // ---- node encoder (encin fused) -> Vf; LN -> Vf + Vh
    mlp3<A_ENCIN, EPI_F, 32><<<gbN, 128, 0, stream>>>(
        nullptr, Wt + OFF_FV1, fv_b1, Wt + OFF_FV2, fv_b2, Wt + OFF_FV3, fv_b3,
        nullptr, Vf, nullptr, nullptr, nullptr, nullptr, nullptr, nullptr,
        pos, area, info, nullptr, N_NODE);
    ln_kernel<<<(N_NODE + 3) / 4, 256, 0, stream>>>(Vf, fv_g, fv_bt, Vh, N_NODE);

    // ---- 15 GNN layers
    for (int l = 0; l < N_LAYER; ++l) {
        mlp3<A_EDGE, EPI_EDGE, 384><<<gbE, 128, 0, stream>>>(
            nullptr,
            Wt + OFF_GE1 + (size_t)l * 49152, ge_b1 + (size_t)l * 128,
            Wt + OFF_GE2 + (size_t)l * 16384, ge_b2 + (size_t)l * 128,
            Wt + OFF_GE3 + (size_t)l * 16384, ge_b3 + (size_t)l * 128,
            Eh, Ef, edges, nullptr, spos, eEs, Vh, Eh,
            nullptr, nullptr, nullptr, nullptr, N_EDGE);
        mlp3<A_NODE, EPI_NODE, 256><<<gbN, 128, 0, stream>>>(
            nullptr,
            Wt + OFF_GN1 + (size_t)l * 32768, gn_b1 + (size_t)l * 128,
            Wt + OFF_GN2 + (size_t)l * 16384, gn_b2 + (size_t)l * 128,
            Wt + OFF_GN3 + (size_t)l * 16384, gn_b3 + (size_t)l * 128,
            Vh, Vf, nullptr, rowptr, nullptr, eEs, Vh, nullptr,
            nullptr, nullptr, nullptr, nullptr, N_NODE);
    }

    // ---- decoder
    mlp3<A_BF16, EPI_DEC, 128><<<gbN, 128, 0, stream>>>(
        Vh, Wt + OFF_DE1, de_b1, Wt + OFF_DE2, de_b2, nullptr, de_b3,
        nullptr, (float*)d_out, nullptr, nullptr, nullptr, nullptr, nullptr, nullptr,
        nullptr, nullptr, nullptr, de_w3, N_NODE);
}